// Round 6
// baseline (268.228 us; speedup 1.0000x reference)
//
#include <hip/hip_runtime.h>
#include <cstdint>

// Problem constants (fixed by setup_inputs): B=4, N=16384, P=1024, C=128
#define BQ_B 4
#define BQ_N 16384
#define BQ_P 1024
#define BQ_C 128
#define NS   64
#define R2   0.04f

// Output layout (flat concat, fp32):
//   region 1: new_features (B,131,P,NS)
//   region 2: grouped_xyz  (B,3,P,NS)
//   region 3: idx0         (B,P,NS) stored as float
#define O1 ((size_t)BQ_B * 131 * BQ_P * NS)
#define O2 (O1 + (size_t)BQ_B * 3 * BQ_P * NS)

// ---------------- Kernel 1: ball query + xyz outputs + gidx->ws ----------------
// 256 threads = 4 waves, one block per center. Round-based cooperative scan:
// per round the block evaluates 4096 points (4 waves x 16 chunks of 64,
// independent loads); masks -> LDS; wave 0 prefix-sums the 64 chunk counts;
// all waves scatter ranked hit indices. Exit at round granularity.
__global__ __launch_bounds__(256) void ballquery_kernel(
    const float* __restrict__ xyz,      // (B, N, 3)
    const float* __restrict__ new_xyz,  // (B, P, 3)
    int* __restrict__ wsIdx,            // (B*P, NS) gather index (BQ_N = pad)
    float* __restrict__ out)
{
#pragma clang fp contract(off)   // match np reference exactly at the radius boundary
    const int center = blockIdx.x;
    const int b = center >> 10;
    const int p = center & (BQ_P - 1);
    const int t = threadIdx.x;
    const int lane = t & 63;
    const int w = t >> 6;               // wave 0..3

    __shared__ unsigned long long smask[64];   // per-chunk hit masks (this round)
    __shared__ int sprefix[64];                // exclusive rank base per chunk
    __shared__ int s_total;                    // total hits so far
    __shared__ int lds_idx[NS];                // first NS ascending hit indices

    const float cx = new_xyz[center * 3 + 0];
    const float cy = new_xyz[center * 3 + 1];
    const float cz = new_xyz[center * 3 + 2];
    const float* xb = xyz + (size_t)b * BQ_N * 3;

    int total = 0;
    const unsigned long long lmask = (1ull << lane) - 1ull;

    for (int round = 0; round < 4; ++round) {
        const int rbase = round * 4096;
        #pragma unroll
        for (int k = 0; k < 16; ++k) {
            const int j = w * 16 + k;
            const int i = rbase + j * 64 + lane;
            const float dx = xb[i * 3 + 0] - cx;
            const float dy = xb[i * 3 + 1] - cy;
            const float dz = xb[i * 3 + 2] - cz;
            const float d2 = dx * dx + dy * dy + dz * dz;
            const unsigned long long m = __ballot(d2 < R2);
            if (lane == 0) smask[j] = m;
        }
        __syncthreads();   // all masks visible

        if (w == 0) {      // prefix-sum 64 chunk counts
            const unsigned long long mm = smask[lane];
            const int cnt = (int)__popcll(mm);
            int x = cnt;
            #pragma unroll
            for (int d = 1; d < 64; d <<= 1) {
                const int y = __shfl_up(x, d, 64);
                if (lane >= d) x += y;
            }
            sprefix[lane] = total + (x - cnt);
            if (lane == 63) s_total = total + x;
        }
        __syncthreads();   // sprefix/s_total visible

        const int new_total = s_total;
        #pragma unroll
        for (int k = 0; k < 16; ++k) {
            const int j = w * 16 + k;
            const unsigned long long m = smask[j];
            const int baser = sprefix[j];
            if (baser < NS && ((m >> lane) & 1ull)) {
                const int r = baser + (int)__popcll(m & lmask);
                if (r < NS) lds_idx[r] = rbase + j * 64 + lane;
            }
        }
        total = new_total;
        if (new_total >= NS) break;
    }
    __syncthreads();

    // ---- slot assignment + idx0 / grouped_xyz / xyz_feature outputs ----
    if (t < NS) {
        const int tt = (total > NS) ? NS : total;
        const int first = (total > 0) ? lds_idx[0] : BQ_N;
        const int v = (t < tt) ? lds_idx[t] : BQ_N;   // BQ_N = pad slot
        const int idx0 = (t < tt) ? v : first;
        const bool real = v < BQ_N;

        wsIdx[(size_t)center * NS + t] = v;
        out[O2 + (size_t)center * NS + t] = (float)idx0;

        #pragma unroll
        for (int d = 0; d < 3; ++d) {
            const float c = (d == 0) ? cx : ((d == 1) ? cy : cz);
            const float pt = real ? xb[v * 3 + d] : 1000000.0f;
            const float g = pt - c;
            out[O1 + ((size_t)(b * 3 + d) * BQ_P + p) * NS + t] = g;
            const float xf = ((g > 100000.0f) ? 0.0f : g) / 0.2f;
            out[((size_t)(b * 131 + d) * BQ_P + p) * NS + t] = xf;
        }
    }
}

// ---------------- Kernel 2: channel-slice feature gather ----------------
// One block per (slice S = b*128+c, p-chunk pc of 128 centers).
// No LDS, no barriers: 32 independent idx-load -> gather -> store chains
// per thread. idx reads and output stores fully coalesced; gathers hit a
// 64 KB L2/L3-resident slice. blockIdx swizzled so all 8 pc-blocks of a
// slice share an XCD (round-robin bi % 8) for L2 slice reuse.
__global__ __launch_bounds__(256) void slice_gather_kernel(
    const float* __restrict__ feats,    // (B, C, N) original layout
    const int* __restrict__ wsIdx,      // (B*P, NS)
    float* __restrict__ out)
{
    const int bi = blockIdx.x;
    const int g8 = bi >> 6;             // slice group (64 slices of 8)
    const int pc = (bi >> 3) & 7;       // p-chunk 0..7 (128 centers each)
    const int s8 = bi & 7;              // slice-within-group == XCD select
    const int S  = g8 * 8 + s8;         // b*128 + c
    const int b  = S >> 7;
    const int c  = S & 127;

    const float* slice = feats + (size_t)S * BQ_N;            // feats[b][c][:]
    const int* idxp = wsIdx + ((size_t)(b * BQ_P) + pc * 128) * NS;
    float* op = out + ((size_t)(b * 131 + 3 + c) * BQ_P + pc * 128) * NS;

    #pragma unroll 8
    for (int k = 0; k < 32; ++k) {
        const int f = k * 256 + threadIdx.x;   // flat (center, slot) in chunk
        const int gi = idxp[f];
        op[f] = (gi < BQ_N) ? slice[gi] : 0.0f;
    }
}

extern "C" void kernel_launch(void* const* d_in, const int* in_sizes, int n_in,
                              void* d_out, int out_size, void* d_ws, size_t ws_size,
                              hipStream_t stream) {
    const float* xyz      = (const float*)d_in[0];  // (4,16384,3)
    const float* new_xyz  = (const float*)d_in[1];  // (4,1024,3)
    const float* features = (const float*)d_in[2];  // (4,128,16384)
    float* out = (float*)d_out;
    int* wsIdx = (int*)d_ws;                        // 1 MB

    ballquery_kernel<<<dim3(BQ_B * BQ_P), dim3(256), 0, stream>>>(xyz, new_xyz, wsIdx, out);
    slice_gather_kernel<<<dim3(BQ_B * BQ_C * 8), dim3(256), 0, stream>>>(features, wsIdx, out);
}

// Round 7
// 227.866 us; speedup vs baseline: 1.1771x; 1.1771x over previous
//
#include <hip/hip_runtime.h>
#include <cstdint>

// Problem constants (fixed by setup_inputs): B=4, N=16384, P=1024, C=128
#define BQ_B 4
#define BQ_N 16384
#define BQ_P 1024
#define BQ_C 128
#define NS   64
#define R2   0.04f

// Output layout (flat concat, fp32):
//   region 1: new_features (B,131,P,NS)
//   region 2: grouped_xyz  (B,3,P,NS)
//   region 3: idx0         (B,P,NS) stored as float
#define O1 ((size_t)BQ_B * 131 * BQ_P * NS)
#define O2 (O1 + (size_t)BQ_B * 3 * BQ_P * NS)

// ws layout: [0, 33.5MB) transposed features (B,N,C); then wsIdx (1 MB)
#define WS_T_BYTES ((size_t)BQ_B * BQ_N * BQ_C * 4)

// ---------------- Kernel 1: features (B,C,N) -> ws (B,N,C) ----------------
__global__ __launch_bounds__(256) void transpose_kernel(
    const float* __restrict__ f, float* __restrict__ ft)
{
    const int bid = blockIdx.x;
    const int n0 = (bid & 255) * 64;
    const int c0 = ((bid >> 8) & 1) * 64;
    const int b  = bid >> 9;
    __shared__ float tile[64][65];

    const float* fb = f + ((size_t)b * BQ_C + c0) * BQ_N;
    #pragma unroll
    for (int k = 0; k < 16; ++k) {
        const int cc = k * 4 + (threadIdx.x >> 6);
        const int nn = threadIdx.x & 63;
        tile[cc][nn] = fb[(size_t)cc * BQ_N + n0 + nn];
    }
    __syncthreads();
    float* ob = ft + ((size_t)b * BQ_N + n0) * BQ_C + c0;
    #pragma unroll
    for (int k = 0; k < 16; ++k) {
        const int nn = k * 4 + (threadIdx.x >> 6);
        const int cc = threadIdx.x & 63;
        ob[(size_t)nn * BQ_C + cc] = tile[cc][nn];
    }
}

// ---------------- Kernel 2: ball query + xyz outputs + gidx->ws ----------------
// 256 threads = 4 waves, one block per center. Round-based cooperative scan.
__global__ __launch_bounds__(256) void ballquery_kernel(
    const float* __restrict__ xyz,      // (B, N, 3)
    const float* __restrict__ new_xyz,  // (B, P, 3)
    int* __restrict__ wsIdx,            // (B*P, NS) gather index (BQ_N = pad)
    float* __restrict__ out)
{
#pragma clang fp contract(off)   // match np reference exactly at the radius boundary
    const int center = blockIdx.x;
    const int b = center >> 10;
    const int p = center & (BQ_P - 1);
    const int t = threadIdx.x;
    const int lane = t & 63;
    const int w = t >> 6;               // wave 0..3

    __shared__ unsigned long long smask[64];   // per-chunk hit masks (this round)
    __shared__ int sprefix[64];                // exclusive rank base per chunk
    __shared__ int s_total;                    // total hits so far
    __shared__ int lds_idx[NS];                // first NS ascending hit indices

    const float cx = new_xyz[center * 3 + 0];
    const float cy = new_xyz[center * 3 + 1];
    const float cz = new_xyz[center * 3 + 2];
    const float* xb = xyz + (size_t)b * BQ_N * 3;

    int total = 0;
    const unsigned long long lmask = (1ull << lane) - 1ull;

    for (int round = 0; round < 4; ++round) {
        const int rbase = round * 4096;
        #pragma unroll
        for (int k = 0; k < 16; ++k) {
            const int j = w * 16 + k;
            const int i = rbase + j * 64 + lane;
            const float dx = xb[i * 3 + 0] - cx;
            const float dy = xb[i * 3 + 1] - cy;
            const float dz = xb[i * 3 + 2] - cz;
            const float d2 = dx * dx + dy * dy + dz * dz;
            const unsigned long long m = __ballot(d2 < R2);
            if (lane == 0) smask[j] = m;
        }
        __syncthreads();   // all masks visible

        if (w == 0) {      // prefix-sum 64 chunk counts
            const unsigned long long mm = smask[lane];
            const int cnt = (int)__popcll(mm);
            int x = cnt;
            #pragma unroll
            for (int d = 1; d < 64; d <<= 1) {
                const int y = __shfl_up(x, d, 64);
                if (lane >= d) x += y;
            }
            sprefix[lane] = total + (x - cnt);
            if (lane == 63) s_total = total + x;
        }
        __syncthreads();   // sprefix/s_total visible

        const int new_total = s_total;
        #pragma unroll
        for (int k = 0; k < 16; ++k) {
            const int j = w * 16 + k;
            const unsigned long long m = smask[j];
            const int baser = sprefix[j];
            if (baser < NS && ((m >> lane) & 1ull)) {
                const int r = baser + (int)__popcll(m & lmask);
                if (r < NS) lds_idx[r] = rbase + j * 64 + lane;
            }
        }
        total = new_total;
        if (new_total >= NS) break;
    }
    __syncthreads();

    if (t < NS) {
        const int tt = (total > NS) ? NS : total;
        const int first = (total > 0) ? lds_idx[0] : BQ_N;
        const int v = (t < tt) ? lds_idx[t] : BQ_N;   // BQ_N = pad slot
        const int idx0 = (t < tt) ? v : first;
        const bool real = v < BQ_N;

        wsIdx[(size_t)center * NS + t] = v;
        out[O2 + (size_t)center * NS + t] = (float)idx0;

        #pragma unroll
        for (int d = 0; d < 3; ++d) {
            const float c = (d == 0) ? cx : ((d == 1) ? cy : cz);
            const float pt = real ? xb[v * 3 + d] : 1000000.0f;
            const float g = pt - c;
            out[O1 + ((size_t)(b * 3 + d) * BQ_P + p) * NS + t] = g;
            const float xf = ((g > 100000.0f) ? 0.0f : g) / 0.2f;
            out[((size_t)(b * 131 + d) * BQ_P + p) * NS + t] = xf;
        }
    }
}

// ---------------- Kernel 3: row gather from transposed features ----------------
// One block per center, 256 threads. float4 row loads (512 B fully-used per
// gathered point), LDS tile transpose (pitch 129), float4 slot-major stores.
// Only 3 barriers; no scan work — memory-pure blocks overlap each other.
__global__ __launch_bounds__(256) void row_gather_kernel(
    const float* __restrict__ ft,       // (B, N, C) transposed
    const int* __restrict__ wsIdx,      // (B*P, NS)
    float* __restrict__ out)
{
    const int center = blockIdx.x;
    const int b = center >> 10;
    const int p = center & (BQ_P - 1);
    const int t = threadIdx.x;

    __shared__ int   sg[NS];
    __shared__ float tile[NS][BQ_C + 1];   // pitch 129

    if (t < NS) sg[t] = wsIdx[(size_t)center * NS + t];
    __syncthreads();

    const float* fb = ft + (size_t)b * BQ_N * BQ_C;
    // load: 8 rows/iter (2 rows per wave-instr), float4 per thread
    #pragma unroll
    for (int k = 0; k < 8; ++k) {
        const int s  = k * 8 + (t >> 5);
        const int c4 = (t & 31) * 4;
        const int gi = sg[s];
        float4 v = make_float4(0.f, 0.f, 0.f, 0.f);
        if (gi < BQ_N) v = *(const float4*)(fb + (size_t)gi * BQ_C + c4);
        tile[s][c4 + 0] = v.x;
        tile[s][c4 + 1] = v.y;
        tile[s][c4 + 2] = v.z;
        tile[s][c4 + 3] = v.w;
    }
    __syncthreads();
    // store: 16 channels/iter, float4 over 4 consecutive slots (256 B segs)
    float* op = out + ((size_t)(b * 131 + 3) * BQ_P + p) * NS;
    #pragma unroll
    for (int k = 0; k < 8; ++k) {
        const int c  = k * 16 + (t >> 4);
        const int s4 = (t & 15) * 4;
        float4 v = make_float4(tile[s4 + 0][c], tile[s4 + 1][c],
                               tile[s4 + 2][c], tile[s4 + 3][c]);
        *(float4*)(op + (size_t)c * (BQ_P * NS) + s4) = v;
    }
}

extern "C" void kernel_launch(void* const* d_in, const int* in_sizes, int n_in,
                              void* d_out, int out_size, void* d_ws, size_t ws_size,
                              hipStream_t stream) {
    const float* xyz      = (const float*)d_in[0];  // (4,16384,3)
    const float* new_xyz  = (const float*)d_in[1];  // (4,1024,3)
    const float* features = (const float*)d_in[2];  // (4,128,16384)
    float* out = (float*)d_out;
    float* ft    = (float*)d_ws;
    int*   wsIdx = (int*)((char*)d_ws + WS_T_BYTES);

    transpose_kernel<<<dim3(BQ_B * 2 * 256), dim3(256), 0, stream>>>(features, ft);
    ballquery_kernel<<<dim3(BQ_B * BQ_P), dim3(256), 0, stream>>>(xyz, new_xyz, wsIdx, out);
    row_gather_kernel<<<dim3(BQ_B * BQ_P), dim3(256), 0, stream>>>(ft, wsIdx, out);
}